// Round 12
// baseline (137.842 us; speedup 1.0000x reference)
//
#include <hip/hip_runtime.h>
#include <hip/hip_bf16.h>
#include <math.h>

typedef short short8 __attribute__((ext_vector_type(8)));
typedef float f32x4 __attribute__((ext_vector_type(4)));
typedef int i32x4 __attribute__((ext_vector_type(4)));

#define NN 8192
#define FIN 256
#define FOUT 128
#define LRELU_A 0.2f
#define L2E 1.44269504088896f

__device__ __forceinline__ short f2bf(float x) {
    unsigned u = __builtin_bit_cast(unsigned, x);
    unsigned r = (u + 0x7FFFu + ((u >> 16) & 1u)) >> 16;   // RNE
    return (short)r;
}

__device__ __forceinline__ short f2bf_fast(float x) {
    return __builtin_bit_cast(short, __float2bfloat16(x));
}

// K1: fused prep. Per block (8 rows): Wh = h@W (fp32) -> WhT (bf16 col-major),
// f1, f2; then pack the same 8 adj rows -> bitmask. The adj HBM stream
// overlaps other blocks' FMA phases.
__global__ __launch_bounds__(256) void k_prep(const float* __restrict__ h,
                                              const float* __restrict__ W,
                                              const float* __restrict__ a,
                                              const int* __restrict__ adj,
                                              short* __restrict__ WhT,
                                              float* __restrict__ f1,
                                              float* __restrict__ f2,
                                              unsigned* __restrict__ packed) {
    __shared__ float hs[8][FIN];
    __shared__ unsigned char nib[2048];
    const int tid = threadIdx.x;
    const int r0 = blockIdx.x * 8;

    // ---- phase 1: Wh / f1 / f2 ----
    #pragma unroll
    for (int i = 0; i < 2; ++i) {
        int f4 = tid + 256 * i;
        int row = f4 >> 6;
        int k4 = (f4 & 63) << 2;
        *(float4*)&hs[row][k4] = *(const float4*)(h + (size_t)(r0 + row) * FIN + k4);
    }
    __syncthreads();
    const int c4 = (tid & 31) * 4;
    const int row = tid >> 5;
    float acc0 = 0.f, acc1 = 0.f, acc2 = 0.f, acc3 = 0.f;
    #pragma unroll 4
    for (int k = 0; k < FIN; ++k) {
        float hv = hs[row][k];
        float4 w4 = *(const float4*)(W + (size_t)k * FOUT + c4);
        acc0 = fmaf(hv, w4.x, acc0);
        acc1 = fmaf(hv, w4.y, acc1);
        acc2 = fmaf(hv, w4.z, acc2);
        acc3 = fmaf(hv, w4.w, acc3);
    }
    const int wr = r0 + row;
    WhT[(size_t)(c4 + 0) * NN + wr] = f2bf(acc0);
    WhT[(size_t)(c4 + 1) * NN + wr] = f2bf(acc1);
    WhT[(size_t)(c4 + 2) * NN + wr] = f2bf(acc2);
    WhT[(size_t)(c4 + 3) * NN + wr] = f2bf(acc3);

    float4 a1v = *(const float4*)(a + c4);
    float4 a2v = *(const float4*)(a + FOUT + c4);
    float p1 = acc0 * a1v.x + acc1 * a1v.y + acc2 * a1v.z + acc3 * a1v.w;
    float p2 = acc0 * a2v.x + acc1 * a2v.y + acc2 * a2v.z + acc3 * a2v.w;
    #pragma unroll
    for (int m = 1; m <= 16; m <<= 1) {
        p1 += __shfl_xor(p1, m, 64);
        p2 += __shfl_xor(p2, m, 64);
    }
    if ((tid & 31) == 0) {
        f1[wr] = p1;
        f2[wr] = p2;
    }

    // ---- phase 2: pack 8 adj rows (coalesced 4KB/wave-inst) ----
    const i32x4* abase = (const i32x4*)(adj + (size_t)r0 * NN);
    for (int r = 0; r < 8; ++r) {
        #pragma unroll
        for (int q = 0; q < 8; ++q) {
            int idx = q * 256 + tid;
            i32x4 v = __builtin_nontemporal_load(abase + (size_t)r * 2048 + idx);
            unsigned b = (unsigned)(v.x & 1)        | ((unsigned)(v.y & 1) << 1) |
                         ((unsigned)(v.z & 1) << 2) | ((unsigned)(v.w & 1) << 3);
            nib[idx] = (unsigned char)b;
        }
        __syncthreads();
        unsigned long long n8 = *(const unsigned long long*)&nib[tid * 8];
        unsigned w = 0;
        #pragma unroll
        for (int j = 0; j < 8; ++j)
            w |= ((unsigned)((n8 >> (8 * j)) & 0xFull)) << (4 * j);
        packed[(size_t)(r0 + r) * (NN / 32) + tid] = w;
        __syncthreads();
    }
}

// K1c: gmax = max(f2)
__global__ __launch_bounds__(256) void k_gmax(const float* __restrict__ f2,
                                              float* __restrict__ gmax) {
    const int tid = threadIdx.x;
    float m = -1e30f;
    for (int i = tid; i < NN; i += 256) m = fmaxf(m, f2[i]);
    #pragma unroll
    for (int s = 1; s <= 32; s <<= 1) m = fmaxf(m, __shfl_xor(m, s, 64));
    __shared__ float red[4];
    if ((tid & 63) == 0) red[tid >> 6] = m;
    __syncthreads();
    if (tid == 0) gmax[0] = fmaxf(fmaxf(red[0], red[1]), fmaxf(red[2], red[3]));
}

// body: 32 cols x 32 rows. One B-fragment read set (8 x ds_read_b128)
// feeds TWO A-fragments (rows lo: base..+15, hi: +16..+31) -> 18 MFMAs.
__device__ __forceinline__ void gat_body2(const short* __restrict__ lrd,
                                          unsigned m8L, unsigned m8H,
                                          float4 fa, float4 fb,
                                          float c1L, float c2L,
                                          float c1H, float c2H,
                                          f32x4 accL[9], f32x4 accH[9],
                                          short8 ones) {
    short8 b0 = *(const short8*)(lrd + 0 * 1024);
    short8 b1 = *(const short8*)(lrd + 1 * 1024);
    short8 b2 = *(const short8*)(lrd + 2 * 1024);
    short8 b3 = *(const short8*)(lrd + 3 * 1024);
    short8 b4 = *(const short8*)(lrd + 4 * 1024);
    short8 b5 = *(const short8*)(lrd + 5 * 1024);
    short8 b6 = *(const short8*)(lrd + 6 * 1024);
    short8 b7 = *(const short8*)(lrd + 7 * 1024);

    float fv[8] = {fa.x, fa.y, fa.z, fa.w, fb.x, fb.y, fb.z, fb.w};
    short8 afL, afH;
    #pragma unroll
    for (int i = 0; i < 8; ++i) {
        float u = fv[i] + c1L;
        float v = fmaf(LRELU_A, fv[i], c2L);
        float p = __builtin_amdgcn_exp2f(fmaxf(u, v));
        afL[i] = f2bf_fast((m8L & (1u << i)) ? p : 0.0f);
    }
    accL[0] = __builtin_amdgcn_mfma_f32_16x16x32_bf16(afL, b0, accL[0], 0, 0, 0);
    accL[1] = __builtin_amdgcn_mfma_f32_16x16x32_bf16(afL, b1, accL[1], 0, 0, 0);
    accL[2] = __builtin_amdgcn_mfma_f32_16x16x32_bf16(afL, b2, accL[2], 0, 0, 0);
    accL[3] = __builtin_amdgcn_mfma_f32_16x16x32_bf16(afL, b3, accL[3], 0, 0, 0);
    accL[4] = __builtin_amdgcn_mfma_f32_16x16x32_bf16(afL, b4, accL[4], 0, 0, 0);
    accL[5] = __builtin_amdgcn_mfma_f32_16x16x32_bf16(afL, b5, accL[5], 0, 0, 0);
    accL[6] = __builtin_amdgcn_mfma_f32_16x16x32_bf16(afL, b6, accL[6], 0, 0, 0);
    accL[7] = __builtin_amdgcn_mfma_f32_16x16x32_bf16(afL, b7, accL[7], 0, 0, 0);
    accL[8] = __builtin_amdgcn_mfma_f32_16x16x32_bf16(afL, ones, accL[8], 0, 0, 0);

    #pragma unroll
    for (int i = 0; i < 8; ++i) {
        float u = fv[i] + c1H;
        float v = fmaf(LRELU_A, fv[i], c2H);
        float p = __builtin_amdgcn_exp2f(fmaxf(u, v));
        afH[i] = f2bf_fast((m8H & (1u << i)) ? p : 0.0f);
    }
    accH[0] = __builtin_amdgcn_mfma_f32_16x16x32_bf16(afH, b0, accH[0], 0, 0, 0);
    accH[1] = __builtin_amdgcn_mfma_f32_16x16x32_bf16(afH, b1, accH[1], 0, 0, 0);
    accH[2] = __builtin_amdgcn_mfma_f32_16x16x32_bf16(afH, b2, accH[2], 0, 0, 0);
    accH[3] = __builtin_amdgcn_mfma_f32_16x16x32_bf16(afH, b3, accH[3], 0, 0, 0);
    accH[4] = __builtin_amdgcn_mfma_f32_16x16x32_bf16(afH, b4, accH[4], 0, 0, 0);
    accH[5] = __builtin_amdgcn_mfma_f32_16x16x32_bf16(afH, b5, accH[5], 0, 0, 0);
    accH[6] = __builtin_amdgcn_mfma_f32_16x16x32_bf16(afH, b6, accH[6], 0, 0, 0);
    accH[7] = __builtin_amdgcn_mfma_f32_16x16x32_bf16(afH, b7, accH[7], 0, 0, 0);
    accH[8] = __builtin_amdgcn_mfma_f32_16x16x32_bf16(afH, ones, accH[8], 0, 0, 0);
}

// One pipeline step (64 cols): mask pairs (lo/hi rows) prefetched last step;
// stage next WhT tile (full-line reg loads -> ds_write at end); f2*L2E from
// LDS; one lgkm-only barrier per step.
#define GAT_STEP(KOFF, MCL, MCH, LRD0, LRD1, BUFW)                                 \
    {                                                                              \
        const int koff_ = (KOFF);                                                  \
        float4 fa0 = *(const float4*)(lf2 + koff_);                                \
        float4 fb0 = *(const float4*)(lf2 + koff_ + 4);                            \
        float4 fa1 = *(const float4*)(lf2 + koff_ + 32);                           \
        float4 fb1 = *(const float4*)(lf2 + koff_ + 36);                           \
        unsigned m0L = (MCL.x >> mshift) & 0xffu;                                  \
        unsigned m1L = (MCL.y >> mshift) & 0xffu;                                  \
        unsigned m0H = (MCH.x >> mshift) & 0xffu;                                  \
        unsigned m1H = (MCH.y >> mshift) & 0xffu;                                  \
        const int kpm_ = (koff_ + 128 < kchunk) ? koff_ + 128 : 0;                 \
        MCL = *(const uint2*)(pkrowL + (kpm_ >> 5));                               \
        MCH = *(const uint2*)(pkrowH + (kpm_ >> 5));                               \
        const int kst_ = (koff_ + 64 < kchunk) ? koff_ + 64 : 0;                   \
        short8 r0 = *(const short8*)(g00 + kst_);                                  \
        short8 r1 = *(const short8*)(g01 + kst_);                                  \
        short8 r2 = *(const short8*)(g10 + kst_);                                  \
        short8 r3 = *(const short8*)(g11 + kst_);                                  \
        gat_body2(LRD0, m0L, m0H, fa0, fb0, c1L, c2L, c1H, c2H, accL, accH, ones); \
        gat_body2(LRD1, m1L, m1H, fa1, fb1, c1L, c2L, c1H, c2H, accL, accH, ones); \
        *(short8*)((BUFW) + d00) = r0;                                             \
        *(short8*)((BUFW) + d01) = r1;                                             \
        *(short8*)((BUFW) + d10) = r2;                                             \
        *(short8*)((BUFW) + d11) = r3;                                             \
        asm volatile("s_waitcnt lgkmcnt(0)" ::: "memory");                         \
        __builtin_amdgcn_s_barrier();                                              \
    }

// K2: fused mask + leaky_relu + exp + (P @ Wh). 32 rows/wave (dual A-frag),
// 128 rows/block, grid = 64 * splitk.
__global__ __launch_bounds__(256, 2) void k_attn(const unsigned* __restrict__ packed,
                                                 const short* __restrict__ WhT,
                                                 const float* __restrict__ f1,
                                                 const float* __restrict__ f2,
                                                 const float* __restrict__ gmax,
                                                 float* __restrict__ numb,
                                                 float* __restrict__ denb,
                                                 int kchunk, int nsplit) {
    __shared__ __align__(16) short ldsW[2][8192];   // 2 x [128 rows][64 cols], swizzled
    __shared__ __align__(16) float ldsF2[2048];     // f2 * L2E
    const int tid = threadIdx.x;
    const int lane = tid & 63;
    const int wave = tid >> 6;
    const int split = blockIdx.x & (nsplit - 1);
    const int rt = blockIdx.x / nsplit;
    const int rowbase = rt * 128 + wave * 32;
    const int col = lane & 15;
    const int kg = lane >> 4;
    const int arowL = rowbase + col;
    const int arowH = arowL + 16;

    const float gm = gmax[0];
    const float f1L = f1[arowL];
    const float f1H = f1[arowH];
    float t;
    t = f1L + gm;
    const float mhL = fmaxf(t, LRELU_A * t) * L2E;
    const float c1L = fmaf(f1L, L2E, -mhL);
    const float c2L = fmaf(LRELU_A * f1L, L2E, -mhL);
    t = f1H + gm;
    const float mhH = fmaxf(t, LRELU_A * t) * L2E;
    const float c1H = fmaf(f1H, L2E, -mhH);
    const float c2H = fmaf(LRELU_A * f1H, L2E, -mhH);

    const short8 ones = {0x3F80, 0x3F80, 0x3F80, 0x3F80,
                         0x3F80, 0x3F80, 0x3F80, 0x3F80};   // bf16 1.0

    const int kbase0 = split * kchunk;
    const unsigned* pkrowL = packed + (size_t)arowL * (NN / 32) + (kbase0 >> 5);
    const unsigned* pkrowH = packed + (size_t)arowH * (NN / 32) + (kbase0 >> 5);
    const int mshift = kg * 8;
    const float* lf2 = ldsF2 + kg * 8;

    // full-line W staging: row = wave*32 + (lane>>2), 16 rows x 64B/inst.
    const int srow = wave * 32 + (lane >> 2);
    const int sx = srow & 7;
    const short* gsb = WhT + (size_t)srow * NN + kbase0 + (lane & 3) * 8;
    const short* g00 = gsb;
    const short* g01 = gsb + 32;
    const short* g10 = gsb + (size_t)16 * NN;
    const short* g11 = gsb + (size_t)16 * NN + 32;
    const int d00 = srow * 64        + ((((lane & 3) + 0) ^ sx) * 8);
    const int d01 = srow * 64        + ((((lane & 3) + 4) ^ sx) * 8);
    const int d10 = (srow + 16) * 64 + ((((lane & 3) + 0) ^ sx) * 8);
    const int d11 = (srow + 16) * 64 + ((((lane & 3) + 4) ^ sx) * 8);
    short* buf0 = &ldsW[0][0];
    short* buf1 = &ldsW[1][0];

    // compute-read bases (body0 / body1 within a 64-col tile)
    const short* lrdE0 = &ldsW[0][col * 64 + ((kg ^ (col & 7)) * 8)];
    const short* lrdE1 = &ldsW[0][col * 64 + (((kg ^ (col & 7)) * 8) ^ 32)];
    const short* lrdO0 = lrdE0 + 8192;
    const short* lrdO1 = lrdE1 + 8192;

    f32x4 accL[9] = {};
    f32x4 accH[9] = {};

    // prologue: f2*L2E -> LDS; W tile0 -> buf0; mask pairs for tiles 0,1
    for (int i = tid * 4; i < kchunk; i += 1024) {
        float4 v = *(const float4*)(f2 + kbase0 + i);
        v.x *= L2E; v.y *= L2E; v.z *= L2E; v.w *= L2E;
        *(float4*)&ldsF2[i] = v;
    }
    {
        short8 r0 = *(const short8*)(g00);
        short8 r1 = *(const short8*)(g01);
        short8 r2 = *(const short8*)(g10);
        short8 r3 = *(const short8*)(g11);
        *(short8*)(buf0 + d00) = r0;
        *(short8*)(buf0 + d01) = r1;
        *(short8*)(buf0 + d10) = r2;
        *(short8*)(buf0 + d11) = r3;
    }
    uint2 mAL = *(const uint2*)(pkrowL);
    uint2 mAH = *(const uint2*)(pkrowH);
    uint2 mBL = *(const uint2*)(pkrowL + 2);
    uint2 mBH = *(const uint2*)(pkrowH + 2);
    asm volatile("s_waitcnt lgkmcnt(0)" ::: "memory");
    __builtin_amdgcn_s_barrier();

    for (int koff = 0; koff < kchunk; koff += 128) {
        GAT_STEP(koff,      mAL, mAH, lrdE0, lrdE1, buf1);   // compute buf0
        GAT_STEP(koff + 64, mBL, mBH, lrdO0, lrdO1, buf0);   // compute buf1
    }

    const int rsub = (lane >> 4) * 4;
    if (col == 0) {
        #pragma unroll
        for (int r = 0; r < 4; ++r) {
            denb[(size_t)split * NN + rowbase + rsub + r] = accL[8][r];
            denb[(size_t)split * NN + rowbase + 16 + rsub + r] = accH[8][r];
        }
    }

    float* npL = numb + ((size_t)split * NN + rowbase) * FOUT;
    float* npH = npL + (size_t)16 * FOUT;
    #pragma unroll
    for (int tcol = 0; tcol < 8; ++tcol) {
        #pragma unroll
        for (int r = 0; r < 4; ++r) {
            npL[(size_t)(rsub + r) * FOUT + tcol * 16 + col] = accL[tcol][r];
            npH[(size_t)(rsub + r) * FOUT + tcol * 16 + col] = accH[tcol][r];
        }
    }
}

// K3: sum split partials, divide, ELU.
__global__ __launch_bounds__(256) void k_final(const float* __restrict__ numb,
                                               const float* __restrict__ denb,
                                               float* __restrict__ out,
                                               int splitk) {
    const int idx = blockIdx.x * 256 + threadIdx.x;
    const int row = idx >> 7;
    float s = 0.0f, d = 0.0f;
    for (int sp = 0; sp < splitk; ++sp) {
        s += numb[((size_t)sp * NN) * FOUT + idx];
        d += denb[(size_t)sp * NN + row];
    }
    float v = s / d;
    out[idx] = v > 0.0f ? v : expm1f(v);
}

extern "C" void kernel_launch(void* const* d_in, const int* in_sizes, int n_in,
                              void* d_out, int out_size, void* d_ws, size_t ws_size,
                              hipStream_t stream) {
    const float* h = (const float*)d_in[0];
    const int* adj = (const int*)d_in[1];
    const float* W = (const float*)d_in[2];
    const float* a = (const float*)d_in[3];
    float* out = (float*)d_out;

    char* ws = (char*)d_ws;
    size_t off = 0;
    auto alloc = [&](size_t nbytes) {
        char* p = ws + off;
        off = (off + nbytes + 255) & ~(size_t)255;
        return p;
    };
    short* WhT     = (short*)alloc((size_t)FOUT * NN * 2);
    float* f1      = (float*)alloc(NN * 4);
    float* f2      = (float*)alloc(NN * 4);
    float* gmx     = (float*)alloc(256);
    unsigned* pkd  = (unsigned*)alloc((size_t)NN * (NN / 32) * 4);   // 8 MB

    int splitk = 8;
    while (splitk > 4 &&
           off + (size_t)splitk * ((size_t)NN * FOUT * 4 + NN * 4 + 512) > ws_size)
        splitk >>= 1;
    float* numb = (float*)alloc((size_t)splitk * NN * FOUT * 4);
    float* denb = (float*)alloc((size_t)splitk * NN * 4);
    const int kchunk = NN / splitk;

    k_prep<<<NN / 8, 256, 0, stream>>>(h, W, a, adj, WhT, f1, f2, pkd);
    k_gmax<<<1, 256, 0, stream>>>(f2, gmx);
    k_attn<<<(NN / 128) * splitk, 256, 0, stream>>>(pkd, WhT, f1, f2, gmx, numb, denb,
                                                    kchunk, splitk);
    k_final<<<NN * FOUT / 256, 256, 0, stream>>>(numb, denb, out, splitk);
}

// Round 13
// 127.098 us; speedup vs baseline: 1.0845x; 1.0845x over previous
//
#include <hip/hip_runtime.h>
#include <hip/hip_bf16.h>
#include <math.h>

typedef short short8 __attribute__((ext_vector_type(8)));
typedef float f32x4 __attribute__((ext_vector_type(4)));
typedef int i32x4 __attribute__((ext_vector_type(4)));

#define NN 8192
#define FIN 256
#define FOUT 128
#define LRELU_A 0.2f
#define L2E 1.44269504088896f

__device__ __forceinline__ short f2bf(float x) {
    unsigned u = __builtin_bit_cast(unsigned, x);
    unsigned r = (u + 0x7FFFu + ((u >> 16) & 1u)) >> 16;   // RNE
    return (short)r;
}

__device__ __forceinline__ short f2bf_fast(float x) {
    return __builtin_bit_cast(short, __float2bfloat16(x));
}

// K1: heterogeneous prep. Blocks [0,1024): Wh = h@W -> WhT bf16 + f1/f2
// (compute/L2-bound). Blocks [1024, 9216): pack one adj row -> bitmask
// (HBM-bound). Co-resident blocks overlap the two streams.
__global__ __launch_bounds__(256) void k_prep(const float* __restrict__ h,
                                              const float* __restrict__ W,
                                              const float* __restrict__ a,
                                              const int* __restrict__ adj,
                                              short* __restrict__ WhT,
                                              float* __restrict__ f1,
                                              float* __restrict__ f2,
                                              unsigned* __restrict__ packed) {
    __shared__ float hs[8][FIN];
    __shared__ unsigned char nib[2048];
    const int tid = threadIdx.x;
    const int bid = blockIdx.x;

    if (bid >= NN / 8) {
        // ---- pack part: one adj row, fully coalesced ----
        const int row = bid - NN / 8;
        const i32x4* base = (const i32x4*)(adj + (size_t)row * NN);
        #pragma unroll
        for (int q = 0; q < 8; ++q) {
            int idx = q * 256 + tid;
            i32x4 v = __builtin_nontemporal_load(base + idx);
            unsigned b = (unsigned)(v.x & 1)        | ((unsigned)(v.y & 1) << 1) |
                         ((unsigned)(v.z & 1) << 2) | ((unsigned)(v.w & 1) << 3);
            nib[idx] = (unsigned char)b;
        }
        __syncthreads();
        unsigned long long n8 = *(const unsigned long long*)&nib[tid * 8];
        unsigned w = 0;
        #pragma unroll
        for (int j = 0; j < 8; ++j)
            w |= ((unsigned)((n8 >> (8 * j)) & 0xFull)) << (4 * j);
        packed[(size_t)row * (NN / 32) + tid] = w;
        return;
    }

    // ---- Wh part: 8 rows ----
    const int r0 = bid * 8;
    #pragma unroll
    for (int i = 0; i < 2; ++i) {
        int f4 = tid + 256 * i;
        int row = f4 >> 6;
        int k4 = (f4 & 63) << 2;
        *(float4*)&hs[row][k4] = *(const float4*)(h + (size_t)(r0 + row) * FIN + k4);
    }
    __syncthreads();
    const int c4 = (tid & 31) * 4;
    const int row = tid >> 5;
    float acc0 = 0.f, acc1 = 0.f, acc2 = 0.f, acc3 = 0.f;
    #pragma unroll 4
    for (int k = 0; k < FIN; ++k) {
        float hv = hs[row][k];
        float4 w4 = *(const float4*)(W + (size_t)k * FOUT + c4);
        acc0 = fmaf(hv, w4.x, acc0);
        acc1 = fmaf(hv, w4.y, acc1);
        acc2 = fmaf(hv, w4.z, acc2);
        acc3 = fmaf(hv, w4.w, acc3);
    }
    const int wr = r0 + row;
    WhT[(size_t)(c4 + 0) * NN + wr] = f2bf(acc0);
    WhT[(size_t)(c4 + 1) * NN + wr] = f2bf(acc1);
    WhT[(size_t)(c4 + 2) * NN + wr] = f2bf(acc2);
    WhT[(size_t)(c4 + 3) * NN + wr] = f2bf(acc3);

    float4 a1v = *(const float4*)(a + c4);
    float4 a2v = *(const float4*)(a + FOUT + c4);
    float p1 = acc0 * a1v.x + acc1 * a1v.y + acc2 * a1v.z + acc3 * a1v.w;
    float p2 = acc0 * a2v.x + acc1 * a2v.y + acc2 * a2v.z + acc3 * a2v.w;
    #pragma unroll
    for (int m = 1; m <= 16; m <<= 1) {
        p1 += __shfl_xor(p1, m, 64);
        p2 += __shfl_xor(p2, m, 64);
    }
    if ((tid & 31) == 0) {
        f1[wr] = p1;
        f2[wr] = p2;
    }
}

// K1c: gmax = max(f2)
__global__ __launch_bounds__(256) void k_gmax(const float* __restrict__ f2,
                                              float* __restrict__ gmax) {
    const int tid = threadIdx.x;
    float m = -1e30f;
    for (int i = tid; i < NN; i += 256) m = fmaxf(m, f2[i]);
    #pragma unroll
    for (int s = 1; s <= 32; s <<= 1) m = fmaxf(m, __shfl_xor(m, s, 64));
    __shared__ float red[4];
    if ((tid & 63) == 0) red[tid >> 6] = m;
    __syncthreads();
    if (tid == 0) gmax[0] = fmaxf(fmaxf(red[0], red[1]), fmaxf(red[2], red[3]));
}

// body: 32 cols. u = fv+c1, v = fma(0.2,fv,c2), p = exp2(max(u,v)), mask,
// bf16; 8 MFMA into acc[0..7] + 1 MFMA with ones into acc[8] (den = P@1).
__device__ __forceinline__ void gat_body(const short* __restrict__ lrd, unsigned m8,
                                         float4 fa, float4 fb,
                                         float c1, float c2,
                                         f32x4 acc[9], short8 ones) {
    short8 b0 = *(const short8*)(lrd + 0 * 1024);
    short8 b1 = *(const short8*)(lrd + 1 * 1024);
    short8 b2 = *(const short8*)(lrd + 2 * 1024);
    short8 b3 = *(const short8*)(lrd + 3 * 1024);
    short8 b4 = *(const short8*)(lrd + 4 * 1024);
    short8 b5 = *(const short8*)(lrd + 5 * 1024);
    short8 b6 = *(const short8*)(lrd + 6 * 1024);
    short8 b7 = *(const short8*)(lrd + 7 * 1024);

    float fv[8] = {fa.x, fa.y, fa.z, fa.w, fb.x, fb.y, fb.z, fb.w};
    short8 af;
    #pragma unroll
    for (int i = 0; i < 8; ++i) {
        float u = fv[i] + c1;
        float v = fmaf(LRELU_A, fv[i], c2);
        float p = __builtin_amdgcn_exp2f(fmaxf(u, v));
        p = (m8 & (1u << i)) ? p : 0.0f;
        af[i] = f2bf_fast(p);
    }
    acc[0] = __builtin_amdgcn_mfma_f32_16x16x32_bf16(af, b0, acc[0], 0, 0, 0);
    acc[1] = __builtin_amdgcn_mfma_f32_16x16x32_bf16(af, b1, acc[1], 0, 0, 0);
    acc[2] = __builtin_amdgcn_mfma_f32_16x16x32_bf16(af, b2, acc[2], 0, 0, 0);
    acc[3] = __builtin_amdgcn_mfma_f32_16x16x32_bf16(af, b3, acc[3], 0, 0, 0);
    acc[4] = __builtin_amdgcn_mfma_f32_16x16x32_bf16(af, b4, acc[4], 0, 0, 0);
    acc[5] = __builtin_amdgcn_mfma_f32_16x16x32_bf16(af, b5, acc[5], 0, 0, 0);
    acc[6] = __builtin_amdgcn_mfma_f32_16x16x32_bf16(af, b6, acc[6], 0, 0, 0);
    acc[7] = __builtin_amdgcn_mfma_f32_16x16x32_bf16(af, b7, acc[7], 0, 0, 0);
    acc[8] = __builtin_amdgcn_mfma_f32_16x16x32_bf16(af, ones, acc[8], 0, 0, 0);
}

// One pipeline step (64 cols): masks from packed word pair (prefetched last
// step); stage next WhT tile (full-line reg loads -> ds_write at step end);
// f2*L2E from LDS; one lgkm-only barrier per step.
#define GAT_STEP(KOFF, MC, LRD0, LRD1, BUFW)                                       \
    {                                                                              \
        const int koff_ = (KOFF);                                                  \
        float4 fa0 = *(const float4*)(lf2 + koff_);                                \
        float4 fb0 = *(const float4*)(lf2 + koff_ + 4);                            \
        float4 fa1 = *(const float4*)(lf2 + koff_ + 32);                           \
        float4 fb1 = *(const float4*)(lf2 + koff_ + 36);                           \
        unsigned m0 = (MC.x >> mshift) & 0xffu;                                    \
        unsigned m1 = (MC.y >> mshift) & 0xffu;                                    \
        const int kpm_ = (koff_ + 128 < kchunk) ? koff_ + 128 : 0;                 \
        MC = *(const uint2*)(pkrow + (kpm_ >> 5));                                 \
        const int kst_ = (koff_ + 64 < kchunk) ? koff_ + 64 : 0;                   \
        short8 r0 = *(const short8*)(g00 + kst_);                                  \
        short8 r1 = *(const short8*)(g01 + kst_);                                  \
        short8 r2 = *(const short8*)(g10 + kst_);                                  \
        short8 r3 = *(const short8*)(g11 + kst_);                                  \
        gat_body(LRD0, m0, fa0, fb0, c1, c2, acc, ones);                           \
        gat_body(LRD1, m1, fa1, fb1, c1, c2, acc, ones);                           \
        *(short8*)((BUFW) + d00) = r0;                                             \
        *(short8*)((BUFW) + d01) = r1;                                             \
        *(short8*)((BUFW) + d10) = r2;                                             \
        *(short8*)((BUFW) + d11) = r3;                                             \
        asm volatile("s_waitcnt lgkmcnt(0)" ::: "memory");                         \
        __builtin_amdgcn_s_barrier();                                              \
    }

// K2: fused mask + leaky_relu + exp + (P @ Wh) via mfma_f32_16x16x32_bf16.
// Round-11 structure: 16 rows/wave, 64 rows/block, 4 blocks/CU.
__global__ __launch_bounds__(256, 4) void k_attn(const unsigned* __restrict__ packed,
                                                 const short* __restrict__ WhT,
                                                 const float* __restrict__ f1,
                                                 const float* __restrict__ f2,
                                                 const float* __restrict__ gmax,
                                                 float* __restrict__ numb,
                                                 float* __restrict__ denb,
                                                 int kchunk, int nsplit) {
    __shared__ __align__(16) short ldsW[2][8192];   // 2 x [128 rows][64 cols], swizzled
    __shared__ __align__(16) float ldsF2[2048];     // f2 * L2E
    const int tid = threadIdx.x;
    const int lane = tid & 63;
    const int wave = tid >> 6;
    const int split = blockIdx.x & (nsplit - 1);
    const int rt = blockIdx.x / nsplit;
    const int rowbase = rt * 64 + wave * 16;
    const int col = lane & 15;
    const int kg = lane >> 4;
    const int arow = rowbase + col;

    const float f1r = f1[arow];
    const float gm = gmax[0];
    const float t0v = f1r + gm;
    const float mhat = fmaxf(t0v, LRELU_A * t0v);   // row-max upper bound
    const float mh2 = mhat * L2E;
    const float c1 = fmaf(f1r, L2E, -mh2);
    const float c2 = fmaf(LRELU_A * f1r, L2E, -mh2);

    const short8 ones = {0x3F80, 0x3F80, 0x3F80, 0x3F80,
                         0x3F80, 0x3F80, 0x3F80, 0x3F80};   // bf16 1.0

    const int kbase0 = split * kchunk;
    const unsigned* pkrow = packed + (size_t)arow * (NN / 32) + (kbase0 >> 5);
    const int mshift = kg * 8;
    const float* lf2 = ldsF2 + kg * 8;

    // full-line W staging: row = wave*32 + (lane>>2), 16 rows x 64B/inst.
    const int srow = wave * 32 + (lane >> 2);
    const int sx = srow & 7;
    const short* gsb = WhT + (size_t)srow * NN + kbase0 + (lane & 3) * 8;
    const short* g00 = gsb;
    const short* g01 = gsb + 32;
    const short* g10 = gsb + (size_t)16 * NN;
    const short* g11 = gsb + (size_t)16 * NN + 32;
    const int d00 = srow * 64        + ((((lane & 3) + 0) ^ sx) * 8);
    const int d01 = srow * 64        + ((((lane & 3) + 4) ^ sx) * 8);
    const int d10 = (srow + 16) * 64 + ((((lane & 3) + 0) ^ sx) * 8);
    const int d11 = (srow + 16) * 64 + ((((lane & 3) + 4) ^ sx) * 8);
    short* buf0 = &ldsW[0][0];
    short* buf1 = &ldsW[1][0];

    // compute-read bases (body0 / body1 within a 64-col tile)
    const short* lrdE0 = &ldsW[0][col * 64 + ((kg ^ (col & 7)) * 8)];
    const short* lrdE1 = &ldsW[0][col * 64 + (((kg ^ (col & 7)) * 8) ^ 32)];
    const short* lrdO0 = lrdE0 + 8192;
    const short* lrdO1 = lrdE1 + 8192;

    f32x4 acc[9] = {};

    // prologue: f2*L2E -> LDS; W tile0 -> buf0; mask pairs for tiles 0,1
    for (int i = tid * 4; i < kchunk; i += 1024) {
        float4 v = *(const float4*)(f2 + kbase0 + i);
        v.x *= L2E; v.y *= L2E; v.z *= L2E; v.w *= L2E;
        *(float4*)&ldsF2[i] = v;
    }
    {
        short8 r0 = *(const short8*)(g00);
        short8 r1 = *(const short8*)(g01);
        short8 r2 = *(const short8*)(g10);
        short8 r3 = *(const short8*)(g11);
        *(short8*)(buf0 + d00) = r0;
        *(short8*)(buf0 + d01) = r1;
        *(short8*)(buf0 + d10) = r2;
        *(short8*)(buf0 + d11) = r3;
    }
    uint2 mA = *(const uint2*)(pkrow);
    uint2 mB = *(const uint2*)(pkrow + 2);
    asm volatile("s_waitcnt lgkmcnt(0)" ::: "memory");
    __builtin_amdgcn_s_barrier();

    for (int koff = 0; koff < kchunk; koff += 128) {
        GAT_STEP(koff,      mA, lrdE0, lrdE1, buf1);   // compute buf0, stage buf1
        GAT_STEP(koff + 64, mB, lrdO0, lrdO1, buf0);   // compute buf1, stage buf0
    }

    const int rsub = (lane >> 4) * 4;
    // den = P @ ones: acc[8][r] holds den[rowbase+rsub+r] (any col; use col==0)
    if (col == 0) {
        #pragma unroll
        for (int r = 0; r < 4; ++r)
            denb[(size_t)split * NN + rowbase + rsub + r] = acc[8][r];
    }

    float* np = numb + ((size_t)split * NN + rowbase) * FOUT;
    #pragma unroll
    for (int t = 0; t < 8; ++t) {
        #pragma unroll
        for (int r = 0; r < 4; ++r) {
            np[(size_t)(rsub + r) * FOUT + t * 16 + col] = acc[t][r];
        }
    }
}

// K3: sum split partials, divide, ELU.
__global__ __launch_bounds__(256) void k_final(const float* __restrict__ numb,
                                               const float* __restrict__ denb,
                                               float* __restrict__ out,
                                               int splitk) {
    const int idx = blockIdx.x * 256 + threadIdx.x;
    const int row = idx >> 7;
    float s = 0.0f, d = 0.0f;
    for (int sp = 0; sp < splitk; ++sp) {
        s += numb[((size_t)sp * NN) * FOUT + idx];
        d += denb[(size_t)sp * NN + row];
    }
    float v = s / d;
    out[idx] = v > 0.0f ? v : expm1f(v);
}

extern "C" void kernel_launch(void* const* d_in, const int* in_sizes, int n_in,
                              void* d_out, int out_size, void* d_ws, size_t ws_size,
                              hipStream_t stream) {
    const float* h = (const float*)d_in[0];
    const int* adj = (const int*)d_in[1];
    const float* W = (const float*)d_in[2];
    const float* a = (const float*)d_in[3];
    float* out = (float*)d_out;

    char* ws = (char*)d_ws;
    size_t off = 0;
    auto alloc = [&](size_t nbytes) {
        char* p = ws + off;
        off = (off + nbytes + 255) & ~(size_t)255;
        return p;
    };
    short* WhT     = (short*)alloc((size_t)FOUT * NN * 2);
    float* f1      = (float*)alloc(NN * 4);
    float* f2      = (float*)alloc(NN * 4);
    float* gmx     = (float*)alloc(256);
    unsigned* pkd  = (unsigned*)alloc((size_t)NN * (NN / 32) * 4);   // 8 MB

    int splitk = 8;
    while (splitk > 1 &&
           off + (size_t)splitk * ((size_t)NN * FOUT * 4 + NN * 4 + 512) > ws_size)
        splitk >>= 1;
    float* numb = (float*)alloc((size_t)splitk * NN * FOUT * 4);
    float* denb = (float*)alloc((size_t)splitk * NN * 4);
    const int kchunk = NN / splitk;

    k_prep<<<NN / 8 + NN, 256, 0, stream>>>(h, W, a, adj, WhT, f1, f2, pkd);
    k_gmax<<<1, 256, 0, stream>>>(f2, gmx);
    k_attn<<<(NN / 64) * splitk, 256, 0, stream>>>(pkd, WhT, f1, f2, gmx, numb, denb,
                                                   kchunk, splitk);
    k_final<<<NN * FOUT / 256, 256, 0, stream>>>(numb, denb, out, splitk);
}